// Round 1
// baseline (63.039 us; speedup 1.0000x reference)
//
#include <hip/hip_runtime.h>

// counts[b,s] = #{t <= s : x[b,t] == x[b,s]}  (inclusive), B=4, S=4096.
// Strategy: brute-force tiled comparison, chunk-parallel with float atomics.
//   grid = (chunk c, query-tile qt, batch b); block active iff c <= qt.
//   Each block: 256 queries (one per thread) vs 256-element chunk staged in LDS.
//   All lanes read the same LDS word per step -> broadcast (conflict-free).
//   Diagonal chunk uses predicated k<=tid mask (wave-uniform trip count).

#define SEQ 4096
#define QT  256   // queries per block
#define CT  256   // chunk elements

__global__ __launch_bounds__(256)
void zero_out_kernel(float4* __restrict__ out) {
    out[blockIdx.x * 256 + threadIdx.x] = make_float4(0.f, 0.f, 0.f, 0.f);
}

__global__ __launch_bounds__(256)
void count_partial_kernel(const int* __restrict__ x, float* __restrict__ out) {
    const int c  = blockIdx.x;   // t-chunk index
    const int qt = blockIdx.y;   // query tile index
    const int b  = blockIdx.z;   // batch row
    if (c > qt) return;          // only t <= s contributes

    const int tid = threadIdx.x;
    const int* __restrict__ row = x + b * SEQ;
    const int s = qt * QT + tid;
    const int q = row[s];

    __shared__ int tile[CT];
    tile[tid] = row[c * CT + tid];
    __syncthreads();

    int cnt = 0;
    if (c < qt) {
        // full chunk: every t in chunk is <= s
        #pragma unroll 8
        for (int k = 0; k < CT; k += 4) {
            int4 a = *reinterpret_cast<const int4*>(&tile[k]);
            cnt += (q == a.x) + (q == a.y) + (q == a.z) + (q == a.w);
        }
    } else {
        // diagonal chunk: local index k qualifies iff k <= tid (includes self)
        #pragma unroll 8
        for (int k = 0; k < CT; k += 4) {
            int4 a = *reinterpret_cast<const int4*>(&tile[k]);
            cnt += (int)((k + 0 <= tid) & (q == a.x))
                 + (int)((k + 1 <= tid) & (q == a.y))
                 + (int)((k + 2 <= tid) & (q == a.z))
                 + (int)((k + 3 <= tid) & (q == a.w));
        }
    }
    atomicAdd(&out[b * SEQ + s], (float)cnt);
}

extern "C" void kernel_launch(void* const* d_in, const int* in_sizes, int n_in,
                              void* d_out, int out_size, void* d_ws, size_t ws_size,
                              hipStream_t stream) {
    const int* x = (const int*)d_in[0];
    float* out = (float*)d_out;
    const int B = in_sizes[0] / SEQ;   // 4

    // zero d_out (harness poisons it with 0xAA before every timed call)
    zero_out_kernel<<<dim3(out_size / (4 * 256)), 256, 0, stream>>>((float4*)out);

    count_partial_kernel<<<dim3(SEQ / CT, SEQ / QT, B), 256, 0, stream>>>(x, out);
}